// Round 3
// baseline (474.692 us; speedup 1.0000x reference)
//
#include <hip/hip_runtime.h>

typedef unsigned short u16;
typedef u16 u16x2 __attribute__((ext_vector_type(2)));
typedef u16 u16x4 __attribute__((ext_vector_type(4)));
typedef u16 u16x8 __attribute__((ext_vector_type(8)));
typedef __bf16 bf16x8 __attribute__((ext_vector_type(8)));
typedef float f32x4 __attribute__((ext_vector_type(4)));
typedef float f32x2 __attribute__((ext_vector_type(2)));

#define MFMA16(A, B, C) __builtin_amdgcn_mfma_f32_16x16x32_bf16(A, B, C, 0, 0, 0)

// Constants: B=2, S=2048, E=512, H=8, HD=64
#define SB 2
#define SS 2048
#define SE 512
#define SH 8
#define SHD 64

__device__ __forceinline__ u16 f2b(float f) {
  union { float f; unsigned u; } v;
  v.f = f;
  unsigned r = v.u + 0x7FFFu + ((v.u >> 16) & 1u);  // RNE to bf16
  return (u16)(r >> 16);
}

__device__ __forceinline__ bf16x8 as_bf16x8(u16x8 v) {
  return __builtin_bit_cast(bf16x8, v);
}

// ---------------------------------------------------------------------------
// Prep 1: X [4096,512] f32 -> Xb bf16 (same layout).
// ---------------------------------------------------------------------------
__global__ __launch_bounds__(256)
void convx_kernel(const float* __restrict__ X, u16* __restrict__ Xb)
{
  const int i = (blockIdx.x * 256 + threadIdx.x) * 4;  // exact fit: 2048 blocks
  const float4 v = *(const float4*)&X[i];
  u16x4 o;
  o[0] = f2b(v.x); o[1] = f2b(v.y); o[2] = f2b(v.z); o[3] = f2b(v.w);
  *(u16x4*)&Xb[i] = o;
}

// ---------------------------------------------------------------------------
// Prep 2: W [512,N] f32 -> Wt [N,512] bf16 (transpose + convert, 32x32 tiles).
// ---------------------------------------------------------------------------
__global__ __launch_bounds__(256)
void wtrans_kernel(const float* __restrict__ in, u16* __restrict__ out, int N)
{
  __shared__ float t[32][33];
  const int tid = threadIdx.x;
  const int r = tid >> 3, c4 = (tid & 7) * 4;
  const int k0 = blockIdx.y * 32, n0 = blockIdx.x * 32;
  const float4 v = *(const float4*)&in[(size_t)(k0 + r) * N + n0 + c4];
  t[r][c4 + 0] = v.x; t[r][c4 + 1] = v.y; t[r][c4 + 2] = v.z; t[r][c4 + 3] = v.w;
  __syncthreads();
  u16x4 o;
  o[0] = f2b(t[c4 + 0][r]);
  o[1] = f2b(t[c4 + 1][r]);
  o[2] = f2b(t[c4 + 2][r]);
  o[3] = f2b(t[c4 + 3][r]);
  *(u16x4*)&out[(n0 + r) * 512 + k0 + c4] = o;
}

// ---------------------------------------------------------------------------
// Unified bf16 GEMM (UNCHANGED from round 2 — control).
// ---------------------------------------------------------------------------
template <int MODE>
__global__ __launch_bounds__(256, 2)
void gemm_kernel(const u16* __restrict__ A, const u16* __restrict__ Bt,
                 const float* __restrict__ bias,
                 u16* __restrict__ Q, u16* __restrict__ K, u16* __restrict__ Vt,
                 float* __restrict__ Out)
{
  __shared__ __align__(16) u16 As[128 * 40];
  __shared__ __align__(16) u16 Bs[128 * 40];
  const int tid  = threadIdx.x;
  const int lane = tid & 63, wave = tid >> 6, quad = lane >> 4, l16 = lane & 15;
  const int m0 = blockIdx.y * 128, n0 = blockIdx.x * 128;
  const int wr = (wave >> 1) * 64, wc = (wave & 1) * 64;
  const int sr = tid >> 2, sc = (tid & 3) * 8;

  const f32x4 z4 = {0.f, 0.f, 0.f, 0.f};
  f32x4 acc[4][4];
#pragma unroll
  for (int i = 0; i < 4; i++)
#pragma unroll
    for (int j = 0; j < 4; j++) acc[i][j] = z4;

  for (int k0 = 0; k0 < 512; k0 += 32) {
    const u16x8 a0 = *(const u16x8*)&A[(m0 + sr) * 512 + k0 + sc];
    const u16x8 a1 = *(const u16x8*)&A[(m0 + 64 + sr) * 512 + k0 + sc];
    const u16x8 b0 = *(const u16x8*)&Bt[(n0 + sr) * 512 + k0 + sc];
    const u16x8 b1 = *(const u16x8*)&Bt[(n0 + 64 + sr) * 512 + k0 + sc];
    __syncthreads();
    *(u16x8*)&As[sr * 40 + sc]        = a0;
    *(u16x8*)&As[(64 + sr) * 40 + sc] = a1;
    *(u16x8*)&Bs[sr * 40 + sc]        = b0;
    *(u16x8*)&Bs[(64 + sr) * 40 + sc] = b1;
    __syncthreads();
    bf16x8 af[4], bf[4];
#pragma unroll
    for (int i = 0; i < 4; i++) {
      af[i] = as_bf16x8(*(const u16x8*)&As[(wr + i * 16 + l16) * 40 + quad * 8]);
      bf[i] = as_bf16x8(*(const u16x8*)&Bs[(wc + i * 16 + l16) * 40 + quad * 8]);
    }
#pragma unroll
    for (int i = 0; i < 4; i++)
#pragma unroll
      for (int j = 0; j < 4; j++) acc[i][j] = MFMA16(af[i], bf[j], acc[i][j]);
  }

#pragma unroll
  for (int tm = 0; tm < 4; tm++) {
#pragma unroll
    for (int tn = 0; tn < 4; tn++) {
#pragma unroll
      for (int r = 0; r < 4; r++) {
        const int gm = m0 + wr + tm * 16 + quad * 4 + r;
        const int gn = n0 + wc + tn * 16 + l16;
        const float v = acc[tm][tn][r] + bias[gn];
        if (MODE == 0) {
          const int bb = gm >> 11, s = gm & 2047;
          const int hh = gn / 192, j = gn - hh * 192;
          const int bh = bb * SH + hh;
          if (j < 64)
            Q[(bh * SS + s) * SHD + j] = f2b(v * 0.125f);
          else if (j < 128)
            K[(bh * SS + s) * SHD + (j - 64)] = f2b(v);
          else
            Vt[(bh * SHD + (j - 128)) * SS + s] = f2b(v);
        } else {
          Out[gm * 512 + gn] = v;
        }
      }
    }
  }
}

// ---------------------------------------------------------------------------
// Fused attention, REWRITTEN: 512 blocks (32 q-tiles x 16 bh), 256 threads =
// 4 waves; each wave owns 16 full query rows. Two passes over K:
//   pass A: online per-lane max/sum (scores discarded), merged by a 4-step
//           16-lane shuffle tree. No barriers, no cross-wave reduction.
//   pass B: recompute scores (bitwise-identical MFMA chain), write normalized
//           fp32 P, bf16 P -> per-wave LDS (stride 268: all-32-bank, 2-way
//           free), PV full contraction per wave, direct O write.
// K/V read per block = 768 KB (vs 512 KB x 4 redundancy before per 16 rows):
// total K/V traffic 1.07 GB -> ~0.19 GB; XCD-swizzle keeps 2 heads (1 MB)
// per XCD L2.
// ---------------------------------------------------------------------------
#define PSTR 268

__global__ __launch_bounds__(256, 2)
void attn_kernel(const u16* __restrict__ Q, const u16* __restrict__ K,
                 const u16* __restrict__ Vt, u16* __restrict__ values,
                 float* __restrict__ attn)
{
  __shared__ __align__(16) u16 p_lds[4][16 * PSTR];  // 34,304 B

  const int tid  = threadIdx.x;
  const int lane = tid & 63, wave = tid >> 6, quad = lane >> 4, l16 = lane & 15;

  // bijective XCD swizzle: 512 wgs, 64 per XCD -> 2 heads per XCD
  const int bid = blockIdx.x;
  const int wg  = (bid & 7) * 64 + (bid >> 3);
  const int qt  = wg & 31;          // q-tile of 64 rows
  const int bh  = wg >> 5;          // 0..15
  const int h = bh & 7, b = bh >> 3;
  const int q0 = qt * 64 + wave * 16;  // this wave's 16 rows

  const u16* Qb = Q + (size_t)bh * SS * SHD;
  const u16* Kb = K + (size_t)bh * SS * SHD;
  const u16* Vb = Vt + (size_t)bh * SHD * SS;

  // Q A-frags for this wave's 16 rows (Q pre-scaled by 1/8)
  const bf16x8 aq0 = as_bf16x8(*(const u16x8*)&Qb[(q0 + l16) * SHD + quad * 8]);
  const bf16x8 aq1 = as_bf16x8(*(const u16x8*)&Qb[(q0 + l16) * SHD + 32 + quad * 8]);

  // ---- pass A: online row stats (per-lane, keys = kt*256 + ct*16 + l16) ----
  float m[4] = {-1e30f, -1e30f, -1e30f, -1e30f};
  float l[4] = {0.f, 0.f, 0.f, 0.f};
  for (int kt = 0; kt < 8; kt++) {
    f32x4 acc[16];
#pragma unroll
    for (int ct = 0; ct < 16; ct++) {
      const int kb = kt * 256 + ct * 16;
      bf16x8 bk0 = as_bf16x8(*(const u16x8*)&Kb[(kb + l16) * SHD + quad * 8]);
      bf16x8 bk1 = as_bf16x8(*(const u16x8*)&Kb[(kb + l16) * SHD + 32 + quad * 8]);
      f32x4 c = {0.f, 0.f, 0.f, 0.f};
      c = MFMA16(aq0, bk0, c);
      c = MFMA16(aq1, bk1, c);
      acc[ct] = c;
    }
#pragma unroll
    for (int r = 0; r < 4; r++) {
      float tm = acc[0][r];
#pragma unroll
      for (int ct = 1; ct < 16; ct++) tm = fmaxf(tm, acc[ct][r]);
      const float mn = fmaxf(m[r], tm);
      float s = 0.f;
#pragma unroll
      for (int ct = 0; ct < 16; ct++) s += __expf(acc[ct][r] - mn);
      l[r] = l[r] * __expf(m[r] - mn) + s;
      m[r] = mn;
    }
  }
  // merge stats across the 16 key-lanes (xor 1,2,4,8 stays in the l16 group)
#pragma unroll
  for (int off = 1; off < 16; off <<= 1) {
#pragma unroll
    for (int r = 0; r < 4; r++) {
      const float m2 = __shfl_xor(m[r], off);
      const float l2 = __shfl_xor(l[r], off);
      const float mn = fmaxf(m[r], m2);
      l[r] = l[r] * __expf(m[r] - mn) + l2 * __expf(m2 - mn);
      m[r] = mn;
    }
  }
  float inv[4];
#pragma unroll
  for (int r = 0; r < 4; r++) inv[r] = 1.f / l[r];

  // ---- pass B: recompute scores, write P, PV ----
  float* attn_b = attn + ((size_t)bh * SS + q0) * SS;
  u16* pl = &p_lds[wave][0];
  f32x4 oacc[4];
#pragma unroll
  for (int nt = 0; nt < 4; nt++) oacc[nt] = (f32x4){0.f, 0.f, 0.f, 0.f};

  for (int kt = 0; kt < 8; kt++) {
    f32x4 acc[16];
#pragma unroll
    for (int ct = 0; ct < 16; ct++) {
      const int kb = kt * 256 + ct * 16;
      bf16x8 bk0 = as_bf16x8(*(const u16x8*)&Kb[(kb + l16) * SHD + quad * 8]);
      bf16x8 bk1 = as_bf16x8(*(const u16x8*)&Kb[(kb + l16) * SHD + 32 + quad * 8]);
      f32x4 c = {0.f, 0.f, 0.f, 0.f};
      c = MFMA16(aq0, bk0, c);
      c = MFMA16(aq1, bk1, c);
      acc[ct] = c;
    }
#pragma unroll
    for (int ct = 0; ct < 16; ct++) {
#pragma unroll
      for (int r = 0; r < 4; r++) {
        const float p = __expf(acc[ct][r] - m[r]) * inv[r];
        attn_b[(quad * 4 + r) * SS + kt * 256 + ct * 16 + l16] = p;
        pl[(quad * 4 + r) * PSTR + ct * 16 + l16] = f2b(p);
      }
    }
    // PV for this 256-key tile (wave-private LDS; in-order via lgkmcnt)
#pragma unroll
    for (int kc = 0; kc < 8; kc++) {
      bf16x8 pa = as_bf16x8(*(const u16x8*)&pl[l16 * PSTR + kc * 32 + quad * 8]);
      const int sb = kt * 256 + kc * 32 + quad * 8;
#pragma unroll
      for (int nt = 0; nt < 4; nt++) {
        bf16x8 vb = as_bf16x8(*(const u16x8*)&Vb[(nt * 16 + l16) * SS + sb]);
        oacc[nt] = MFMA16(pa, vb, oacc[nt]);
      }
    }
  }

  // ---- O write: full contraction done in-wave, no reduction needed ----
#pragma unroll
  for (int nt = 0; nt < 4; nt++) {
#pragma unroll
    for (int r = 0; r < 4; r++) {
      const int qrow = q0 + quad * 4 + r;
      values[((size_t)(b * SS + qrow) * SH + h) * SHD + nt * 16 + l16] =
          f2b(oacc[nt][r]);
    }
  }
}

// ---------------------------------------------------------------------------
// Workspace budget: EXACTLY 16 MiB (= round-0 verified footprint).
//   ws: Q(4MB) K(4MB) Vt(4MB) values(4MB; Xb aliases it)
//   WqkvT: staged in d_out's attn region (dead until attn_kernel overwrites;
//          consumed by qkv gemm which finishes first — stream-serialized).
//   WoT:   aliases the Q region; produced AFTER attn (Q dead), read by oproj.
// ---------------------------------------------------------------------------
extern "C" void kernel_launch(void* const* d_in, const int* in_sizes, int n_in,
                              void* d_out, int out_size, void* d_ws, size_t ws_size,
                              hipStream_t stream) {
  const float* X    = (const float*)d_in[0];
  const float* Wqkv = (const float*)d_in[1];
  const float* bqkv = (const float*)d_in[2];
  const float* Wo   = (const float*)d_in[3];
  const float* bo   = (const float*)d_in[4];

  float* o_out    = (float*)d_out;                       // [2,2048,512]
  float* attn_out = o_out + SB * SS * SE;                // [2,8,2048,2048]

  const size_t QKV_ELEMS = (size_t)SB * SH * SS * SHD;   // 2,097,152 per tensor
  u16* Q      = (u16*)d_ws;
  u16* K      = Q + QKV_ELEMS;
  u16* Vt     = K + QKV_ELEMS;
  u16* values = Vt + QKV_ELEMS;
  u16* Xb     = values;               // dead before attn writes values
  u16* WqkvT  = (u16*)attn_out;       // dead until attn writes attn_out
  u16* WoT    = Q;                    // Q dead after attn; WoT made post-attn

  // Prep: one-shot bf16 conversion / transposition of QKV GEMM operands
  convx_kernel<<<dim3(2048), 256, 0, stream>>>(X, Xb);
  wtrans_kernel<<<dim3(48, 16), 256, 0, stream>>>(Wqkv, WqkvT, 1536);

  // QKV projection: M=4096 (32 m-blocks), N=1536 (12 n-blocks)
  gemm_kernel<0><<<dim3(12, 32), 256, 0, stream>>>(Xb, WqkvT, bqkv, Q, K, Vt, nullptr);
  // Attention: 512 blocks (32 q-tiles x 8 heads x 2 batches), 4 waves each
  attn_kernel<<<dim3(512), 256, 0, stream>>>(Q, K, Vt, values, attn_out);
  // Wo transpose into (now-dead) Q region, then O projection
  wtrans_kernel<<<dim3(16, 16), 256, 0, stream>>>(Wo, WoT, 512);
  gemm_kernel<1><<<dim3(4, 32), 256, 0, stream>>>(values, WoT, bo,
                                                  nullptr, nullptr, nullptr, o_out);
}

// Round 4
// 425.716 us; speedup vs baseline: 1.1150x; 1.1150x over previous
//
#include <hip/hip_runtime.h>

typedef unsigned short u16;
typedef u16 u16x2 __attribute__((ext_vector_type(2)));
typedef u16 u16x4 __attribute__((ext_vector_type(4)));
typedef u16 u16x8 __attribute__((ext_vector_type(8)));
typedef __bf16 bf16x8 __attribute__((ext_vector_type(8)));
typedef float f32x4 __attribute__((ext_vector_type(4)));
typedef float f32x2 __attribute__((ext_vector_type(2)));

#define MFMA16(A, B, C) __builtin_amdgcn_mfma_f32_16x16x32_bf16(A, B, C, 0, 0, 0)

// Constants: B=2, S=2048, E=512, H=8, HD=64
#define SB 2
#define SS 2048
#define SE 512
#define SH 8
#define SHD 64

__device__ __forceinline__ u16 f2b(float f) {
  union { float f; unsigned u; } v;
  v.f = f;
  unsigned r = v.u + 0x7FFFu + ((v.u >> 16) & 1u);  // RNE to bf16
  return (u16)(r >> 16);
}

__device__ __forceinline__ bf16x8 as_bf16x8(u16x8 v) {
  return __builtin_bit_cast(bf16x8, v);
}

// ---------------------------------------------------------------------------
// Prep 1: X [4096,512] f32 -> Xb bf16 (same layout).
// ---------------------------------------------------------------------------
__global__ __launch_bounds__(256)
void convx_kernel(const float* __restrict__ X, u16* __restrict__ Xb)
{
  const int i = (blockIdx.x * 256 + threadIdx.x) * 4;  // exact fit: 2048 blocks
  const float4 v = *(const float4*)&X[i];
  u16x4 o;
  o[0] = f2b(v.x); o[1] = f2b(v.y); o[2] = f2b(v.z); o[3] = f2b(v.w);
  *(u16x4*)&Xb[i] = o;
}

// ---------------------------------------------------------------------------
// Prep 2: W [512,N] f32 -> Wt [N,512] bf16 (transpose + convert, 32x32 tiles).
// ---------------------------------------------------------------------------
__global__ __launch_bounds__(256)
void wtrans_kernel(const float* __restrict__ in, u16* __restrict__ out, int N)
{
  __shared__ float t[32][33];
  const int tid = threadIdx.x;
  const int r = tid >> 3, c4 = (tid & 7) * 4;
  const int k0 = blockIdx.y * 32, n0 = blockIdx.x * 32;
  const float4 v = *(const float4*)&in[(size_t)(k0 + r) * N + n0 + c4];
  t[r][c4 + 0] = v.x; t[r][c4 + 1] = v.y; t[r][c4 + 2] = v.z; t[r][c4 + 3] = v.w;
  __syncthreads();
  u16x4 o;
  o[0] = f2b(t[c4 + 0][r]);
  o[1] = f2b(t[c4 + 1][r]);
  o[2] = f2b(t[c4 + 2][r]);
  o[3] = f2b(t[c4 + 3][r]);
  *(u16x4*)&out[(n0 + r) * 512 + k0 + c4] = o;
}

// ---------------------------------------------------------------------------
// Unified bf16 GEMM (UNCHANGED — control).
// ---------------------------------------------------------------------------
template <int MODE>
__global__ __launch_bounds__(256, 2)
void gemm_kernel(const u16* __restrict__ A, const u16* __restrict__ Bt,
                 const float* __restrict__ bias,
                 u16* __restrict__ Q, u16* __restrict__ K, u16* __restrict__ Vt,
                 float* __restrict__ Out)
{
  __shared__ __align__(16) u16 As[128 * 40];
  __shared__ __align__(16) u16 Bs[128 * 40];
  const int tid  = threadIdx.x;
  const int lane = tid & 63, wave = tid >> 6, quad = lane >> 4, l16 = lane & 15;
  const int m0 = blockIdx.y * 128, n0 = blockIdx.x * 128;
  const int wr = (wave >> 1) * 64, wc = (wave & 1) * 64;
  const int sr = tid >> 2, sc = (tid & 3) * 8;

  const f32x4 z4 = {0.f, 0.f, 0.f, 0.f};
  f32x4 acc[4][4];
#pragma unroll
  for (int i = 0; i < 4; i++)
#pragma unroll
    for (int j = 0; j < 4; j++) acc[i][j] = z4;

  for (int k0 = 0; k0 < 512; k0 += 32) {
    const u16x8 a0 = *(const u16x8*)&A[(m0 + sr) * 512 + k0 + sc];
    const u16x8 a1 = *(const u16x8*)&A[(m0 + 64 + sr) * 512 + k0 + sc];
    const u16x8 b0 = *(const u16x8*)&Bt[(n0 + sr) * 512 + k0 + sc];
    const u16x8 b1 = *(const u16x8*)&Bt[(n0 + 64 + sr) * 512 + k0 + sc];
    __syncthreads();
    *(u16x8*)&As[sr * 40 + sc]        = a0;
    *(u16x8*)&As[(64 + sr) * 40 + sc] = a1;
    *(u16x8*)&Bs[sr * 40 + sc]        = b0;
    *(u16x8*)&Bs[(64 + sr) * 40 + sc] = b1;
    __syncthreads();
    bf16x8 af[4], bf[4];
#pragma unroll
    for (int i = 0; i < 4; i++) {
      af[i] = as_bf16x8(*(const u16x8*)&As[(wr + i * 16 + l16) * 40 + quad * 8]);
      bf[i] = as_bf16x8(*(const u16x8*)&Bs[(wc + i * 16 + l16) * 40 + quad * 8]);
    }
#pragma unroll
    for (int i = 0; i < 4; i++)
#pragma unroll
      for (int j = 0; j < 4; j++) acc[i][j] = MFMA16(af[i], bf[j], acc[i][j]);
  }

#pragma unroll
  for (int tm = 0; tm < 4; tm++) {
#pragma unroll
    for (int tn = 0; tn < 4; tn++) {
#pragma unroll
      for (int r = 0; r < 4; r++) {
        const int gm = m0 + wr + tm * 16 + quad * 4 + r;
        const int gn = n0 + wc + tn * 16 + l16;
        const float v = acc[tm][tn][r] + bias[gn];
        if (MODE == 0) {
          const int bb = gm >> 11, s = gm & 2047;
          const int hh = gn / 192, j = gn - hh * 192;
          const int bh = bb * SH + hh;
          if (j < 64)
            Q[(bh * SS + s) * SHD + j] = f2b(v * 0.125f);
          else if (j < 128)
            K[(bh * SS + s) * SHD + (j - 64)] = f2b(v);
          else
            Vt[(bh * SHD + (j - 128)) * SS + s] = f2b(v);
        } else {
          Out[gm * 512 + gn] = v;
        }
      }
    }
  }
}

// ---------------------------------------------------------------------------
// Fused attention v3: 2048 blocks (128 q-tiles x 8 h x 2 b), 512 thr = 8
// waves. Block owns 16 query rows; wave w owns keys [w*256, w*256+256), all
// scores held in registers (single K pass, no recompute).
//   1. per-wave online stats: in-lane max -> exp -> sum, 16-lane shuffle
//      merge; (m_w, l_w) to LDS.                      [barrier #1]
//   2. global merge per lane; P = p' * exp(m_w-m_g)/l_g; NONTEMPORAL fp32
//      store (266 MB stream, never re-read -> keep K/V L2-resident);
//      bf16 P to wave-private LDS.
//   3. PV per wave (wave-private LDS read, no barrier), partials written
//      into own LDS region.                           [barrier #2]
//   4. cross-wave tree reduce, bf16 values write.
// launch_bounds(512,4): force VGPR<=128 so LDS (68 KB) and VGPR both allow
// 2 blocks/CU = 16 waves/CU (round 3 was grid-capped at 8 waves/CU).
// ---------------------------------------------------------------------------
#define PSTR 264
#define PWAVE (16 * PSTR)   // u16 elems per wave region (8448 B)

__global__ __launch_bounds__(512, 4)
void attn_kernel(const u16* __restrict__ Q, const u16* __restrict__ K,
                 const u16* __restrict__ Vt, u16* __restrict__ values,
                 float* __restrict__ attn)
{
  __shared__ __align__(16) u16 p_lds[8 * PWAVE];  // 67,584 B
  __shared__ float srm[8][16];
  __shared__ float srl[8][16];

  const int tid  = threadIdx.x;
  const int lane = tid & 63, wave = tid >> 6, quad = lane >> 4, l16 = lane & 15;
  const int q0 = blockIdx.x * 16;
  const int h = blockIdx.y, b = blockIdx.z, bh = b * SH + h;

  const u16* Qb = Q + (size_t)bh * SS * SHD;
  const u16* Kb = K + (size_t)bh * SS * SHD;
  const u16* Vb = Vt + (size_t)bh * SHD * SS;

  // Q A-frags (same 16 rows for every wave; Q pre-scaled by 1/8)
  const bf16x8 aq0 = as_bf16x8(*(const u16x8*)&Qb[(q0 + l16) * SHD + quad * 8]);
  const bf16x8 aq1 = as_bf16x8(*(const u16x8*)&Qb[(q0 + l16) * SHD + 32 + quad * 8]);

  // ---- scores: 16 tiles of 16x16 per wave (keys wave*256 + ct*16 + l16) ----
  f32x4 acc[16];
#pragma unroll
  for (int ct = 0; ct < 16; ct++) {
    const int kb = wave * 256 + ct * 16;
    bf16x8 bk0 = as_bf16x8(*(const u16x8*)&Kb[(kb + l16) * SHD + quad * 8]);
    bf16x8 bk1 = as_bf16x8(*(const u16x8*)&Kb[(kb + l16) * SHD + 32 + quad * 8]);
    f32x4 c = {0.f, 0.f, 0.f, 0.f};
    c = MFMA16(aq0, bk0, c);
    c = MFMA16(aq1, bk1, c);
    acc[ct] = c;
  }

  // ---- per-wave stats: local max, exp in place, local sum (pre-barrier) ----
  float mw[4], lw[4];
#pragma unroll
  for (int r = 0; r < 4; r++) {
    float m = acc[0][r];
#pragma unroll
    for (int ct = 1; ct < 16; ct++) m = fmaxf(m, acc[ct][r]);
#pragma unroll
    for (int off = 1; off < 16; off <<= 1) m = fmaxf(m, __shfl_xor(m, off));
    mw[r] = m;
  }
#pragma unroll
  for (int r = 0; r < 4; r++) {
    float s = 0.f;
#pragma unroll
    for (int ct = 0; ct < 16; ct++) {
      const float p = __expf(acc[ct][r] - mw[r]);
      acc[ct][r] = p;           // p' = exp(s - m_w)
      s += p;
    }
#pragma unroll
    for (int off = 1; off < 16; off <<= 1) s += __shfl_xor(s, off);
    lw[r] = s;
  }
  if (l16 == 0) {
#pragma unroll
    for (int r = 0; r < 4; r++) {
      srm[wave][quad * 4 + r] = mw[r];
      srl[wave][quad * 4 + r] = lw[r];
    }
  }
  __syncthreads();  // barrier #1

  // ---- global merge: scale[r] = exp(m_w - m_g) / l_g ----
  float scale[4];
#pragma unroll
  for (int r = 0; r < 4; r++) {
    const int row = quad * 4 + r;
    float mg = srm[0][row];
#pragma unroll
    for (int w = 1; w < 8; w++) mg = fmaxf(mg, srm[w][row]);
    float lg = 0.f;
#pragma unroll
    for (int w = 0; w < 8; w++) lg += srl[w][row] * __expf(srm[w][row] - mg);
    scale[r] = __expf(mw[r] - mg) / lg;
  }

  // ---- normalize: NT fp32 P to d_out, bf16 P to wave-private LDS ----
  float* attn_b = attn + ((size_t)bh * SS + q0) * SS;
  u16* pl = &p_lds[wave * PWAVE];
#pragma unroll
  for (int ct = 0; ct < 16; ct++) {
    const int col = wave * 256 + ct * 16 + l16;
#pragma unroll
    for (int r = 0; r < 4; r++) {
      const float p = acc[ct][r] * scale[r];
      __builtin_nontemporal_store(p, &attn_b[(quad * 4 + r) * SS + col]);
      pl[(quad * 4 + r) * PSTR + ct * 16 + l16] = f2b(p);
    }
  }

  // ---- PV: wave-private LDS reads (in-order via lgkmcnt, no barrier) ----
  f32x4 oacc[4];
#pragma unroll
  for (int nt = 0; nt < 4; nt++) oacc[nt] = (f32x4){0.f, 0.f, 0.f, 0.f};
#pragma unroll
  for (int kc = 0; kc < 8; kc++) {
    bf16x8 pa = as_bf16x8(*(const u16x8*)&pl[l16 * PSTR + kc * 32 + quad * 8]);
    const int sb = wave * 256 + kc * 32 + quad * 8;
#pragma unroll
    for (int nt = 0; nt < 4; nt++) {
      bf16x8 vb = as_bf16x8(*(const u16x8*)&Vb[(nt * 16 + l16) * SS + sb]);
      oacc[nt] = MFMA16(pa, vb, oacc[nt]);
    }
  }

  // ---- partials into own LDS region (wave-private, no pre-barrier) ----
  float* op = (float*)pl;  // 4096 B used of 8448 B region
#pragma unroll
  for (int nt = 0; nt < 4; nt++)
#pragma unroll
    for (int r = 0; r < 4; r++)
      op[(quad * 4 + r) * 64 + nt * 16 + l16] = oacc[nt][r];
  __syncthreads();  // barrier #2

  // ---- cross-wave reduce + values write ----
  const int q = tid >> 5, d0 = (tid & 31) * 2;
  f32x2 s2 = {0.f, 0.f};
#pragma unroll
  for (int w = 0; w < 8; w++) {
    const float* opw = (const float*)&p_lds[w * PWAVE];
    s2 += *(const f32x2*)&opw[q * 64 + d0];
  }
  u16x2 o2;
  o2[0] = f2b(s2[0]);
  o2[1] = f2b(s2[1]);
  *(u16x2*)&values[((size_t)(b * SS + q0 + q) * SH + h) * SHD + d0] = o2;
}

// ---------------------------------------------------------------------------
// Workspace budget: EXACTLY 16 MiB (verified footprint).
//   ws: Q(4MB) K(4MB) Vt(4MB) values(4MB; Xb aliases it)
//   WqkvT: staged in d_out's attn region (dead until attn_kernel overwrites).
//   WoT:   aliases Q region; produced AFTER attn (Q dead), read by oproj.
// ---------------------------------------------------------------------------
extern "C" void kernel_launch(void* const* d_in, const int* in_sizes, int n_in,
                              void* d_out, int out_size, void* d_ws, size_t ws_size,
                              hipStream_t stream) {
  const float* X    = (const float*)d_in[0];
  const float* Wqkv = (const float*)d_in[1];
  const float* bqkv = (const float*)d_in[2];
  const float* Wo   = (const float*)d_in[3];
  const float* bo   = (const float*)d_in[4];

  float* o_out    = (float*)d_out;                       // [2,2048,512]
  float* attn_out = o_out + SB * SS * SE;                // [2,8,2048,2048]

  const size_t QKV_ELEMS = (size_t)SB * SH * SS * SHD;   // 2,097,152 per tensor
  u16* Q      = (u16*)d_ws;
  u16* K      = Q + QKV_ELEMS;
  u16* Vt     = K + QKV_ELEMS;
  u16* values = Vt + QKV_ELEMS;
  u16* Xb     = values;               // dead before attn writes values
  u16* WqkvT  = (u16*)attn_out;       // dead until attn writes attn_out
  u16* WoT    = Q;                    // Q dead after attn; WoT made post-attn

  // Prep: one-shot bf16 conversion / transposition of QKV GEMM operands
  convx_kernel<<<dim3(2048), 256, 0, stream>>>(X, Xb);
  wtrans_kernel<<<dim3(48, 16), 256, 0, stream>>>(Wqkv, WqkvT, 1536);

  // QKV projection: M=4096 (32 m-blocks), N=1536 (12 n-blocks)
  gemm_kernel<0><<<dim3(12, 32), 256, 0, stream>>>(Xb, WqkvT, bqkv, Q, K, Vt, nullptr);
  // Attention: 128 q-tiles x 8 heads x 2 batches, 8 waves each
  attn_kernel<<<dim3(128, 8, 2), 512, 0, stream>>>(Q, K, Vt, values, attn_out);
  // Wo transpose into (now-dead) Q region, then O projection
  wtrans_kernel<<<dim3(16, 16), 256, 0, stream>>>(Wo, WoT, 512);
  gemm_kernel<1><<<dim3(4, 32), 256, 0, stream>>>(values, WoT, bo,
                                                  nullptr, nullptr, nullptr, o_out);
}

// Round 5
// 421.263 us; speedup vs baseline: 1.1268x; 1.0106x over previous
//
#include <hip/hip_runtime.h>

typedef unsigned short u16;
typedef u16 u16x2 __attribute__((ext_vector_type(2)));
typedef u16 u16x4 __attribute__((ext_vector_type(4)));
typedef u16 u16x8 __attribute__((ext_vector_type(8)));
typedef __bf16 bf16x8 __attribute__((ext_vector_type(8)));
typedef float f32x4 __attribute__((ext_vector_type(4)));
typedef float f32x2 __attribute__((ext_vector_type(2)));

#define MFMA16(A, B, C) __builtin_amdgcn_mfma_f32_16x16x32_bf16(A, B, C, 0, 0, 0)

// Constants: B=2, S=2048, E=512, H=8, HD=64
#define SB 2
#define SS 2048
#define SE 512
#define SH 8
#define SHD 64

__device__ __forceinline__ u16 f2b(float f) {
  union { float f; unsigned u; } v;
  v.f = f;
  unsigned r = v.u + 0x7FFFu + ((v.u >> 16) & 1u);  // RNE to bf16
  return (u16)(r >> 16);
}

__device__ __forceinline__ bf16x8 as_bf16x8(u16x8 v) {
  return __builtin_bit_cast(bf16x8, v);
}

// ---------------------------------------------------------------------------
// Merged prep: blocks [0,2048) convert X f32->bf16; blocks [2048,2816)
// transpose+convert Wqkv into WqkvT [1536,512] bf16.
// ---------------------------------------------------------------------------
__global__ __launch_bounds__(256)
void prep_kernel(const float* __restrict__ X, u16* __restrict__ Xb,
                 const float* __restrict__ Wqkv, u16* __restrict__ WqkvT)
{
  __shared__ float t[32][33];
  const int tid = threadIdx.x;
  if (blockIdx.x < 2048) {
    const int i = (blockIdx.x * 256 + tid) * 4;
    const float4 v = *(const float4*)&X[i];
    u16x4 o;
    o[0] = f2b(v.x); o[1] = f2b(v.y); o[2] = f2b(v.z); o[3] = f2b(v.w);
    *(u16x4*)&Xb[i] = o;
  } else {
    const int bx = blockIdx.x - 2048;          // 768 blocks: 48 n x 16 k
    const int n0 = (bx % 48) * 32, k0 = (bx / 48) * 32;
    const int r = tid >> 3, c4 = (tid & 7) * 4;
    const float4 v = *(const float4*)&Wqkv[(size_t)(k0 + r) * 1536 + n0 + c4];
    t[r][c4 + 0] = v.x; t[r][c4 + 1] = v.y; t[r][c4 + 2] = v.z; t[r][c4 + 3] = v.w;
    __syncthreads();
    u16x4 o;
    o[0] = f2b(t[c4 + 0][r]);
    o[1] = f2b(t[c4 + 1][r]);
    o[2] = f2b(t[c4 + 2][r]);
    o[3] = f2b(t[c4 + 3][r]);
    *(u16x4*)&WqkvT[(n0 + r) * 512 + k0 + c4] = o;
  }
}

// ---------------------------------------------------------------------------
// Standalone W transpose (used post-attn for WoT).
// ---------------------------------------------------------------------------
__global__ __launch_bounds__(256)
void wtrans_kernel(const float* __restrict__ in, u16* __restrict__ out, int N)
{
  __shared__ float t[32][33];
  const int tid = threadIdx.x;
  const int r = tid >> 3, c4 = (tid & 7) * 4;
  const int k0 = blockIdx.y * 32, n0 = blockIdx.x * 32;
  const float4 v = *(const float4*)&in[(size_t)(k0 + r) * N + n0 + c4];
  t[r][c4 + 0] = v.x; t[r][c4 + 1] = v.y; t[r][c4 + 2] = v.z; t[r][c4 + 3] = v.w;
  __syncthreads();
  u16x4 o;
  o[0] = f2b(t[c4 + 0][r]);
  o[1] = f2b(t[c4 + 1][r]);
  o[2] = f2b(t[c4 + 2][r]);
  o[3] = f2b(t[c4 + 3][r]);
  *(u16x4*)&out[(n0 + r) * 512 + k0 + c4] = o;
}

// ---------------------------------------------------------------------------
// Unified bf16 GEMM (UNCHANGED — control).
// ---------------------------------------------------------------------------
template <int MODE>
__global__ __launch_bounds__(256, 2)
void gemm_kernel(const u16* __restrict__ A, const u16* __restrict__ Bt,
                 const float* __restrict__ bias,
                 u16* __restrict__ Q, u16* __restrict__ K, u16* __restrict__ Vt,
                 float* __restrict__ Out)
{
  __shared__ __align__(16) u16 As[128 * 40];
  __shared__ __align__(16) u16 Bs[128 * 40];
  const int tid  = threadIdx.x;
  const int lane = tid & 63, wave = tid >> 6, quad = lane >> 4, l16 = lane & 15;
  const int m0 = blockIdx.y * 128, n0 = blockIdx.x * 128;
  const int wr = (wave >> 1) * 64, wc = (wave & 1) * 64;
  const int sr = tid >> 2, sc = (tid & 3) * 8;

  const f32x4 z4 = {0.f, 0.f, 0.f, 0.f};
  f32x4 acc[4][4];
#pragma unroll
  for (int i = 0; i < 4; i++)
#pragma unroll
    for (int j = 0; j < 4; j++) acc[i][j] = z4;

  for (int k0 = 0; k0 < 512; k0 += 32) {
    const u16x8 a0 = *(const u16x8*)&A[(m0 + sr) * 512 + k0 + sc];
    const u16x8 a1 = *(const u16x8*)&A[(m0 + 64 + sr) * 512 + k0 + sc];
    const u16x8 b0 = *(const u16x8*)&Bt[(n0 + sr) * 512 + k0 + sc];
    const u16x8 b1 = *(const u16x8*)&Bt[(n0 + 64 + sr) * 512 + k0 + sc];
    __syncthreads();
    *(u16x8*)&As[sr * 40 + sc]        = a0;
    *(u16x8*)&As[(64 + sr) * 40 + sc] = a1;
    *(u16x8*)&Bs[sr * 40 + sc]        = b0;
    *(u16x8*)&Bs[(64 + sr) * 40 + sc] = b1;
    __syncthreads();
    bf16x8 af[4], bf[4];
#pragma unroll
    for (int i = 0; i < 4; i++) {
      af[i] = as_bf16x8(*(const u16x8*)&As[(wr + i * 16 + l16) * 40 + quad * 8]);
      bf[i] = as_bf16x8(*(const u16x8*)&Bs[(wc + i * 16 + l16) * 40 + quad * 8]);
    }
#pragma unroll
    for (int i = 0; i < 4; i++)
#pragma unroll
      for (int j = 0; j < 4; j++) acc[i][j] = MFMA16(af[i], bf[j], acc[i][j]);
  }

#pragma unroll
  for (int tm = 0; tm < 4; tm++) {
#pragma unroll
    for (int tn = 0; tn < 4; tn++) {
#pragma unroll
      for (int r = 0; r < 4; r++) {
        const int gm = m0 + wr + tm * 16 + quad * 4 + r;
        const int gn = n0 + wc + tn * 16 + l16;
        const float v = acc[tm][tn][r] + bias[gn];
        if (MODE == 0) {
          const int bb = gm >> 11, s = gm & 2047;
          const int hh = gn / 192, j = gn - hh * 192;
          const int bh = bb * SH + hh;
          if (j < 64)
            Q[(bh * SS + s) * SHD + j] = f2b(v * 0.125f);
          else if (j < 128)
            K[(bh * SS + s) * SHD + (j - 64)] = f2b(v);
          else
            Vt[(bh * SHD + (j - 128)) * SS + s] = f2b(v);
        } else {
          Out[gm * 512 + gn] = v;
        }
      }
    }
  }
}

// ---------------------------------------------------------------------------
// Fused attention v5 (reordered): 2048 blocks x 8 waves; block = 16 q-rows,
// wave w = keys [w*256, w*256+256), scores in regs (single K pass).
//   1. QK^T -> per-wave online stats -> (m_w,l_w) to LDS   [barrier #1]
//   2. global merge; acc *= scale (P finalized in regs)
//   3. bf16 P -> wave-private LDS; PV with 2-deep V prefetch
//   4. partials -> own LDS region                          [barrier #2:
//      now drains ~no vmem — the fp32 P stores haven't been issued yet]
//   5. cross-wave reduce, values write
//   6. LAST: 64 NT fp32 P stores per thread; drain at kernel end overlaps
//      the co-resident block's compute (was: drained inside barrier #2).
// ---------------------------------------------------------------------------
#define PSTR 264
#define PWAVE (16 * PSTR)   // u16 elems per wave region (8448 B)

__global__ __launch_bounds__(512, 4)
void attn_kernel(const u16* __restrict__ Q, const u16* __restrict__ K,
                 const u16* __restrict__ Vt, u16* __restrict__ values,
                 float* __restrict__ attn)
{
  __shared__ __align__(16) u16 p_lds[8 * PWAVE];  // 67,584 B
  __shared__ float srm[8][16];
  __shared__ float srl[8][16];

  const int tid  = threadIdx.x;
  const int lane = tid & 63, wave = tid >> 6, quad = lane >> 4, l16 = lane & 15;
  const int q0 = blockIdx.x * 16;
  const int h = blockIdx.y, b = blockIdx.z, bh = b * SH + h;

  const u16* Qb = Q + (size_t)bh * SS * SHD;
  const u16* Kb = K + (size_t)bh * SS * SHD;
  const u16* Vb = Vt + (size_t)bh * SHD * SS;

  const bf16x8 aq0 = as_bf16x8(*(const u16x8*)&Qb[(q0 + l16) * SHD + quad * 8]);
  const bf16x8 aq1 = as_bf16x8(*(const u16x8*)&Qb[(q0 + l16) * SHD + 32 + quad * 8]);

  // ---- scores: 16 tiles of 16x16 per wave ----
  f32x4 acc[16];
#pragma unroll
  for (int ct = 0; ct < 16; ct++) {
    const int kb = wave * 256 + ct * 16;
    bf16x8 bk0 = as_bf16x8(*(const u16x8*)&Kb[(kb + l16) * SHD + quad * 8]);
    bf16x8 bk1 = as_bf16x8(*(const u16x8*)&Kb[(kb + l16) * SHD + 32 + quad * 8]);
    f32x4 c = {0.f, 0.f, 0.f, 0.f};
    c = MFMA16(aq0, bk0, c);
    c = MFMA16(aq1, bk1, c);
    acc[ct] = c;
  }

  // ---- per-wave stats: local max, exp in place, local sum ----
  float mw[4], lw[4];
#pragma unroll
  for (int r = 0; r < 4; r++) {
    float m = acc[0][r];
#pragma unroll
    for (int ct = 1; ct < 16; ct++) m = fmaxf(m, acc[ct][r]);
#pragma unroll
    for (int off = 1; off < 16; off <<= 1) m = fmaxf(m, __shfl_xor(m, off));
    mw[r] = m;
  }
#pragma unroll
  for (int r = 0; r < 4; r++) {
    float s = 0.f;
#pragma unroll
    for (int ct = 0; ct < 16; ct++) {
      const float p = __expf(acc[ct][r] - mw[r]);
      acc[ct][r] = p;           // p' = exp(s - m_w)
      s += p;
    }
#pragma unroll
    for (int off = 1; off < 16; off <<= 1) s += __shfl_xor(s, off);
    lw[r] = s;
  }
  if (l16 == 0) {
#pragma unroll
    for (int r = 0; r < 4; r++) {
      srm[wave][quad * 4 + r] = mw[r];
      srl[wave][quad * 4 + r] = lw[r];
    }
  }
  __syncthreads();  // barrier #1

  // ---- global merge: scale[r] = exp(m_w - m_g) / l_g; finalize P in regs ----
  float scale[4];
#pragma unroll
  for (int r = 0; r < 4; r++) {
    const int row = quad * 4 + r;
    float mg = srm[0][row];
#pragma unroll
    for (int w = 1; w < 8; w++) mg = fmaxf(mg, srm[w][row]);
    float lg = 0.f;
#pragma unroll
    for (int w = 0; w < 8; w++) lg += srl[w][row] * __expf(srm[w][row] - mg);
    scale[r] = __expf(mw[r] - mg) / lg;
  }
#pragma unroll
  for (int ct = 0; ct < 16; ct++)
#pragma unroll
    for (int r = 0; r < 4; r++) acc[ct][r] *= scale[r];

  // ---- bf16 P -> wave-private LDS ----
  u16* pl = &p_lds[wave * PWAVE];
#pragma unroll
  for (int ct = 0; ct < 16; ct++)
#pragma unroll
    for (int r = 0; r < 4; r++)
      pl[(quad * 4 + r) * PSTR + ct * 16 + l16] = f2b(acc[ct][r]);

  // ---- PV with 2-deep V prefetch (static dual buffer, fully unrolled) ----
  f32x4 oacc[4];
#pragma unroll
  for (int nt = 0; nt < 4; nt++) oacc[nt] = (f32x4){0.f, 0.f, 0.f, 0.f};
  bf16x8 vbuf[2][4];
  {
    const int sb = wave * 256 + quad * 8;
#pragma unroll
    for (int nt = 0; nt < 4; nt++)
      vbuf[0][nt] = as_bf16x8(*(const u16x8*)&Vb[(nt * 16 + l16) * SS + sb]);
  }
#pragma unroll
  for (int kc = 0; kc < 8; kc++) {
    if (kc < 7) {
      const int sb = wave * 256 + (kc + 1) * 32 + quad * 8;
#pragma unroll
      for (int nt = 0; nt < 4; nt++)
        vbuf[(kc + 1) & 1][nt] =
            as_bf16x8(*(const u16x8*)&Vb[(nt * 16 + l16) * SS + sb]);
    }
    bf16x8 pa = as_bf16x8(*(const u16x8*)&pl[l16 * PSTR + kc * 32 + quad * 8]);
#pragma unroll
    for (int nt = 0; nt < 4; nt++)
      oacc[nt] = MFMA16(pa, vbuf[kc & 1][nt], oacc[nt]);
  }

  // ---- partials into own LDS region ----
  float* op = (float*)pl;
#pragma unroll
  for (int nt = 0; nt < 4; nt++)
#pragma unroll
    for (int r = 0; r < 4; r++)
      op[(quad * 4 + r) * 64 + nt * 16 + l16] = oacc[nt][r];
  __syncthreads();  // barrier #2 (no pending vmem stores now)

  // ---- cross-wave reduce + values write ----
  const int q = tid >> 5, d0 = (tid & 31) * 2;
  f32x2 s2 = {0.f, 0.f};
#pragma unroll
  for (int w = 0; w < 8; w++) {
    const float* opw = (const float*)&p_lds[w * PWAVE];
    s2 += *(const f32x2*)&opw[q * 64 + d0];
  }
  u16x2 o2;
  o2[0] = f2b(s2[0]);
  o2[1] = f2b(s2[1]);
  *(u16x2*)&values[((size_t)(b * SS + q0 + q) * SH + h) * SHD + d0] = o2;

  // ---- LAST: NT fp32 P stores (fire-and-forget; drain at kernel end) ----
  float* attn_b = attn + ((size_t)bh * SS + q0) * SS;
#pragma unroll
  for (int ct = 0; ct < 16; ct++) {
    const int col = wave * 256 + ct * 16 + l16;
#pragma unroll
    for (int r = 0; r < 4; r++)
      __builtin_nontemporal_store(acc[ct][r], &attn_b[(quad * 4 + r) * SS + col]);
  }
}

// ---------------------------------------------------------------------------
// Workspace budget: EXACTLY 16 MiB (verified footprint).
//   ws: Q(4MB) K(4MB) Vt(4MB) values(4MB; Xb aliases it)
//   WqkvT: staged in d_out's attn region (dead until attn_kernel overwrites).
//   WoT:   aliases Q region; produced AFTER attn (Q dead), read by oproj.
// ---------------------------------------------------------------------------
extern "C" void kernel_launch(void* const* d_in, const int* in_sizes, int n_in,
                              void* d_out, int out_size, void* d_ws, size_t ws_size,
                              hipStream_t stream) {
  const float* X    = (const float*)d_in[0];
  const float* Wqkv = (const float*)d_in[1];
  const float* bqkv = (const float*)d_in[2];
  const float* Wo   = (const float*)d_in[3];
  const float* bo   = (const float*)d_in[4];

  float* o_out    = (float*)d_out;                       // [2,2048,512]
  float* attn_out = o_out + SB * SS * SE;                // [2,8,2048,2048]

  const size_t QKV_ELEMS = (size_t)SB * SH * SS * SHD;   // 2,097,152 per tensor
  u16* Q      = (u16*)d_ws;
  u16* K      = Q + QKV_ELEMS;
  u16* Vt     = K + QKV_ELEMS;
  u16* values = Vt + QKV_ELEMS;
  u16* Xb     = values;               // dead before attn writes values
  u16* WqkvT  = (u16*)attn_out;       // dead until attn writes attn_out
  u16* WoT    = Q;                    // Q dead after attn; WoT made post-attn

  // Merged prep: X conversion + Wqkv transpose (one launch)
  prep_kernel<<<dim3(2816), 256, 0, stream>>>(X, Xb, Wqkv, WqkvT);

  // QKV projection: M=4096 (32 m-blocks), N=1536 (12 n-blocks)
  gemm_kernel<0><<<dim3(12, 32), 256, 0, stream>>>(Xb, WqkvT, bqkv, Q, K, Vt, nullptr);
  // Attention: 128 q-tiles x 8 heads x 2 batches, 8 waves each
  attn_kernel<<<dim3(128, 8, 2), 512, 0, stream>>>(Q, K, Vt, values, attn_out);
  // Wo transpose into (now-dead) Q region, then O projection
  wtrans_kernel<<<dim3(16, 16), 256, 0, stream>>>(Wo, WoT, 512);
  gemm_kernel<1><<<dim3(4, 32), 256, 0, stream>>>(values, WoT, bo,
                                                  nullptr, nullptr, nullptr, o_out);
}